// Round 13
// baseline (296.388 us; speedup 1.0000x reference)
//
#include <hip/hip_runtime.h>
#include <stdint.h>

// D = 128 fixed by the problem.
#define FD 128

typedef __bf16 bf16x8 __attribute__((ext_vector_type(8)));
typedef unsigned short u16x8 __attribute__((ext_vector_type(8)));
typedef float  f32x16 __attribute__((ext_vector_type(16)));

__device__ __forceinline__ unsigned short f2bf(float f) {
    unsigned u = __float_as_uint(f);
    unsigned r = u + 0x7fffu + ((u >> 16) & 1u);   // RNE
    return (unsigned short)(r >> 16);
}
__device__ __forceinline__ float bflo(unsigned u) { return __uint_as_float(u << 16); }
__device__ __forceinline__ float bfhi(unsigned u) { return __uint_as_float(u & 0xffff0000u); }

// ---------------------------------------------------------------------------
// Layouts (R6, kept):
//   A  [N][128] bf16 canonical (gate-rec term + bg folded).
//   BS [N][256] bf16: B row (gate-send) then S row (message + bs) per node.
//
// R13:
//  (1) gemm epilogue: per-wave LDS transpose -> full-line dwordx4 stores at
//      UNCHANGED addresses (R5 showed layout changes kill L2 reuse; this
//      changes only store width). 4-row batches in a private 1-KB region:
//      write = one row per instruction (16 banks x 2-way, free); read =
//      lane*16 linear (m97-proven conflict-free); store = 16 lanes cover a
//      full 256-B row. 64 scalar stores/tile -> 8 dwordx4.
//  (2) scan absorbed into the gemm dispatch (blockIdx.y==5, 98 blocks):
//      hist blocks signal a done-counter; scan blocks spin then run the R9
//      lookback body with memory-side atomic reads of deg. Deadlock-free:
//      gemm/hist blocks never wait, so slots always turn over; <=98 spinners.
//      Pipeline: prep -> gemm(+hist+scan) -> scatter -> aggregate (4 disp).
// Dead ends measured: grid.sync ~93us (R7); per-feature fp32 atomics (R8);
// order-dependent barriers (R10); barrier-fused scatter at 256 blocks (R11).
// ---------------------------------------------------------------------------

// ---------------------------------------------------------------------------
// prep: weights -> Wf (bf16, MFMA B-fragment order) + zero deg/partial.
// ---------------------------------------------------------------------------
__global__ __launch_bounds__(256) void prep_kernel(
    const float* __restrict__ Wg,
    const float* __restrict__ Ws,
    const float* __restrict__ Wr,
    unsigned short* __restrict__ Wf,
    int* __restrict__ deg,
    int* __restrict__ partial,       // [0..255] lookback, [260] hist-done
    int N)
{
    int wid = blockIdx.x * 256 + threadIdx.x;      // 0 .. 65535
    for (int i = wid; i < N; i += 65536) deg[i] = 0;
    if (wid < 264) partial[wid] = 0;
    if (wid >= 512 * 128) return;
    int j  = wid & 7;
    int l  = (wid >> 3) & 63;
    int kt = (wid >> 9) & 7;
    int ct = wid >> 12;                        // 0..15
    int k  = kt * 16 + (l >> 5) * 8 + j;       // 0..127
    int c  = ct * 32 + (l & 31);               // 0..511
    float v;
    if (c < 128)      v = Wg[k * FD + c];                    // Wg1
    else if (c < 256) v = Wg[(128 + k) * FD + (c - 128)];    // Wg2
    else if (c < 384) v = Ws[k * FD + (c - 256)];            // Ws
    else              v = Wr[k * FD + (c - 384)];            // Wr
    Wf[wid] = f2bf(v);
}

// ---------------------------------------------------------------------------
// gemm (+hist +scan slices): [A|B|S|R] = h @ [Wg1|Wg2|Ws|Wr]
// y==0: hist (256 blocks, first -> overlaps gemm) + done-signal.
// y==1..4: gemm, w = y-1 (LDS-stationary weights; new wide-store epilogue).
// y==5: scan slice (98 active blocks; waits for hist-done).
// ---------------------------------------------------------------------------
__global__ __launch_bounds__(256, 4) void gemm_kernel(
    const float* __restrict__ h,
    const unsigned short* __restrict__ Wf,
    const float* __restrict__ bg,
    const float* __restrict__ bs,
    const float* __restrict__ br,
    unsigned short* __restrict__ A,
    unsigned short* __restrict__ BS,
    float* __restrict__ out,
    const int* __restrict__ idx,
    int* __restrict__ deg,
    int* __restrict__ partial,
    int N, int E)
{
    __shared__ unsigned short Bsh[16384];       // 32 KB weights (scan: scratch)
    __shared__ uint4 EshQ[256];                 // 4 KB: 4 waves x 1 KB epilogue

    if (blockIdx.y == 0) {
        // ---- hist slice: 256 blocks, overlaps gemm ----
        int t = blockIdx.x * 256 + threadIdx.x;
        for (int e = t; e < E; e += 65536) atomicAdd(&deg[idx[E + e]], 1);
        __syncthreads();
        __threadfence();
        if (threadIdx.x == 0) atomicAdd(&partial[260], 1);   // done-signal
        return;
    }

    if (blockIdx.y == 5) {
        // ---- scan slice: decoupled-lookback scan of deg (R9 body) ----
        const int nb = (N + 1023) >> 10;        // 98
        if (blockIdx.x >= nb) return;
        if (threadIdx.x == 0) {
            while (atomicAdd(&partial[260], 0) < 256) __builtin_amdgcn_s_sleep(8);
        }
        __syncthreads();
        int* sh  = (int*)Bsh;
        int* sh2 = sh + 256;
        const int bid = blockIdx.x;
        const int tid = threadIdx.x;
        int base = bid * 1024 + tid * 4;
        int v[4];
        #pragma unroll
        for (int j = 0; j < 4; ++j)
            v[j] = (base + j < N) ? atomicAdd(&deg[base + j], 0) : 0;
        int tsum = v[0] + v[1] + v[2] + v[3];
        sh[tid] = tsum;
        __syncthreads();
        for (int ofs = 1; ofs < 256; ofs <<= 1) {
            int x = (tid >= ofs) ? sh[tid - ofs] : 0;
            __syncthreads();
            sh[tid] += x;
            __syncthreads();
        }
        if (tid == 0)
            atomicExch((unsigned*)&partial[bid], 0x80000000u | (unsigned)sh[255]);
        int myagg = 0;
        if (tid < bid) {
            unsigned p;
            do { p = atomicAdd((unsigned*)&partial[tid], 0u); }
            while (!(p & 0x80000000u));
            myagg = (int)(p & 0x7fffffffu);
        }
        sh2[tid] = myagg;
        __syncthreads();
        for (int ofs = 128; ofs > 0; ofs >>= 1) {
            if (tid < ofs) sh2[tid] += sh2[tid + ofs];
            __syncthreads();
        }
        int run = sh2[0] + sh[tid] - tsum;      // global exclusive prefix
        #pragma unroll
        for (int j = 0; j < 4; ++j) {
            if (base + j < N) deg[base + j] = run;   // START offsets (plain;
            run += v[j];                             // flushed at dispatch end)
        }
        return;
    }

    // ---------------------- gemm slice ----------------------
    const int w    = blockIdx.y - 1;            // 0..3: which weight matrix
    const int lane = threadIdx.x & 63;
    const int wid  = threadIdx.x >> 6;          // wave 0..3

    // ---- stage quarter w into LDS once ----
    {
        const unsigned short* src = Wf + (size_t)w * 16384 + (size_t)threadIdx.x * 8;
        unsigned short* dst = Bsh + (size_t)threadIdx.x * 8;
        #pragma unroll
        for (int p = 0; p < 8; ++p) {
            __builtin_amdgcn_global_load_lds(
                (const __attribute__((address_space(1))) void*)(src + p * 2048),
                (__attribute__((address_space(3))) void*)(dst + p * 2048),
                16, 0, 0);
        }
    }

    const int col_l  = lane & 31;
    const int rhalf  = (lane >> 5) * 4;
    float bias[4];
    #pragma unroll
    for (int i = 0; i < 4; ++i) {
        int col = i * 32 + col_l;
        bias[i] = (w == 0) ? bg[col] : (w == 2) ? bs[col] : (w == 3) ? br[col] : 0.0f;
    }
    unsigned short* dst0 = (w == 0) ? A : (w == 2) ? (BS + 128) : BS;
    const size_t rstride = (w == 0) ? 128 : 256;
    unsigned short* eb = (unsigned short*)(EshQ + (size_t)wid * 64);  // 1 KB

    __syncthreads();   // staging complete

    const int stride = gridDim.x * 128;
    for (int rb0 = blockIdx.x * 128; rb0 < N; rb0 += stride) {
        const int rb = rb0 + wid * 32;
        int arow = rb + (lane & 31);
        if (arow >= N) arow = N - 1;
        const float* aptr = h + (size_t)arow * FD + (lane >> 5) * 8;

        bf16x8 afrag[8];
        #pragma unroll
        for (int kt = 0; kt < 8; ++kt) {
            float4 f0 = *(const float4*)(aptr + kt * 16);
            float4 f1 = *(const float4*)(aptr + kt * 16 + 4);
            union { u16x8 u; bf16x8 b; } cv;
            cv.u[0] = f2bf(f0.x); cv.u[1] = f2bf(f0.y);
            cv.u[2] = f2bf(f0.z); cv.u[3] = f2bf(f0.w);
            cv.u[4] = f2bf(f1.x); cv.u[5] = f2bf(f1.y);
            cv.u[6] = f2bf(f1.z); cv.u[7] = f2bf(f1.w);
            afrag[kt] = cv.b;
        }

        f32x16 acc[4];
        #pragma unroll
        for (int i = 0; i < 4; ++i)
            #pragma unroll
            for (int r = 0; r < 16; ++r) acc[i][r] = 0.0f;

        #pragma unroll
        for (int kt = 0; kt < 8; ++kt) {
            #pragma unroll
            for (int i = 0; i < 4; ++i) {
                bf16x8 bfr = *(const bf16x8*)(Bsh + (size_t)((i * 8 + kt) * 64 + lane) * 8);
                acc[i] = __builtin_amdgcn_mfma_f32_32x32x16_bf16(
                             afrag[kt], bfr, acc[i], 0, 0, 0);
            }
        }

        // C/D layout: col = lane&31, row = (reg&3) + 8*(reg>>2) + 4*(lane>>5)
        //   reg r = 4b+j covers global row rb + 8b + j + rhalf.
        const bool interior = (rb + 32 <= N);
        if (w == 3) {
            // fp32 out: already full 128-B segments per store; old path.
            #pragma unroll
            for (int i = 0; i < 4; ++i) {
                int col = i * 32 + col_l;
                #pragma unroll
                for (int r = 0; r < 16; ++r) {
                    int row = rb + (r & 3) + 8 * (r >> 2) + rhalf;
                    if (interior || row < N)
                        out[(size_t)row * FD + col] = acc[i][r] + bias[i];
                }
            }
        } else {
            // Wide-store epilogue: 8 batches of 4 rows. Batch q covers rows
            // rb+4q..rb+4q+3, written by the half-wave with rhalf==4*(q&1).
            #pragma unroll
            for (int q = 0; q < 8; ++q) {
                const int b = q >> 1;
                const bool mine = ((lane >> 5) == (q & 1));
                if (interior) {
                    if (mine) {
                        #pragma unroll
                        for (int j = 0; j < 4; ++j) {
                            #pragma unroll
                            for (int i = 0; i < 4; ++i)
                                eb[j * 128 + i * 32 + col_l] =
                                    f2bf(acc[i][4 * b + j] + bias[i]);
                        }
                    }
                } else {
                    if (mine) {
                        #pragma unroll
                        for (int j = 0; j < 4; ++j) {
                            int row = rb + 4 * q + j;
                            if (row < N) {
                                #pragma unroll
                                for (int i = 0; i < 4; ++i)
                                    dst0[(size_t)row * rstride + i * 32 + col_l] =
                                        f2bf(acc[i][4 * b + j] + bias[i]);
                            }
                        }
                    }
                }
                __syncthreads();
                if (interior) {
                    // read back linearly (lane*16 B) and store full lines:
                    // 16 lanes cover one 256-B row.
                    int lr = lane >> 4;                 // 0..3
                    int c  = lane & 15;
                    uint4 vq = *(const uint4*)((const char*)eb + lane * 16);
                    int grow = rb + 4 * q + lr;
                    *(uint4*)(dst0 + (size_t)grow * rstride + c * 8) = vq;
                }
                __syncthreads();
            }
        }
    }
}

// scatter: full-width (1 thread/edge). csr[pos] = send, consuming off
// (after: off[r] = end of segment r; start = (r==0) ? 0 : off[r-1]).
__global__ __launch_bounds__(256) void scatter_kernel(
    const int* __restrict__ idx, int* __restrict__ off,
    int* __restrict__ csr, int E)
{
    int e = blockIdx.x * 256 + threadIdx.x;
    if (e >= E) return;
    int s = idx[e];
    int r = idx[E + e];
    int pos = atomicAdd(&off[r], 1);
    csr[pos] = s;
}

// ---------------------------------------------------------------------------
// aggregate: R6 form verbatim (proven 64 us).
// ---------------------------------------------------------------------------
__global__ __launch_bounds__(256) void aggregate_kernel(
    const int* __restrict__ off,          // off[r] = segment end
    const int* __restrict__ csr,
    const unsigned* __restrict__ A,       // bf16x2 per uint, [N][64]
    const unsigned* __restrict__ BS,      // bf16x2 per uint, [N][128] (B|S)
    float* __restrict__ out,
    int N)
{
    int r = blockIdx.x * 4 + (threadIdx.x >> 6);
    if (r >= N) return;
    int lane = threadIdx.x & 63;

    int start = (r == 0) ? 0 : off[r - 1];
    int end   = off[r];
    if (start >= end) return;             // deg 0: out already holds R

    unsigned ua = A[(size_t)r * 64 + lane];
    float a0 = bflo(ua), a1 = bfhi(ua);
    float acc0 = 0.0f, acc1 = 0.0f;

    int i = start;
    for (; i + 3 < end; i += 4) {
        int s0 = csr[i], s1 = csr[i + 1], s2 = csr[i + 2], s3 = csr[i + 3];
        unsigned ub0 = BS[(size_t)s0 * 128 + lane];
        unsigned us0 = BS[(size_t)s0 * 128 + 64 + lane];
        unsigned ub1 = BS[(size_t)s1 * 128 + lane];
        unsigned us1 = BS[(size_t)s1 * 128 + 64 + lane];
        unsigned ub2 = BS[(size_t)s2 * 128 + lane];
        unsigned us2 = BS[(size_t)s2 * 128 + 64 + lane];
        unsigned ub3 = BS[(size_t)s3 * 128 + lane];
        unsigned us3 = BS[(size_t)s3 * 128 + 64 + lane];
        acc0 += bflo(us0) * __builtin_amdgcn_rcpf(1.0f + __expf(-(a0 + bflo(ub0))));
        acc1 += bfhi(us0) * __builtin_amdgcn_rcpf(1.0f + __expf(-(a1 + bfhi(ub0))));
        acc0 += bflo(us1) * __builtin_amdgcn_rcpf(1.0f + __expf(-(a0 + bflo(ub1))));
        acc1 += bfhi(us1) * __builtin_amdgcn_rcpf(1.0f + __expf(-(a1 + bfhi(ub1))));
        acc0 += bflo(us2) * __builtin_amdgcn_rcpf(1.0f + __expf(-(a0 + bflo(ub2))));
        acc1 += bfhi(us2) * __builtin_amdgcn_rcpf(1.0f + __expf(-(a1 + bfhi(ub2))));
        acc0 += bflo(us3) * __builtin_amdgcn_rcpf(1.0f + __expf(-(a0 + bflo(ub3))));
        acc1 += bfhi(us3) * __builtin_amdgcn_rcpf(1.0f + __expf(-(a1 + bfhi(ub3))));
    }
    for (; i < end; ++i) {
        int s0 = csr[i];
        unsigned ub0 = BS[(size_t)s0 * 128 + lane];
        unsigned us0 = BS[(size_t)s0 * 128 + 64 + lane];
        acc0 += bflo(us0) * __builtin_amdgcn_rcpf(1.0f + __expf(-(a0 + bflo(ub0))));
        acc1 += bfhi(us0) * __builtin_amdgcn_rcpf(1.0f + __expf(-(a1 + bfhi(ub0))));
    }

    float2* o = (float2*)(out + (size_t)r * FD + 2 * lane);
    float2 cur = *o;
    cur.x += acc0;
    cur.y += acc1;
    *o = cur;
}

// ---------------------------------------------------------------------------
extern "C" void kernel_launch(void* const* d_in, const int* in_sizes, int n_in,
                              void* d_out, int out_size, void* d_ws, size_t ws_size,
                              hipStream_t stream)
{
    const float* h  = (const float*)d_in[0];
    const int*   ei = (const int*)d_in[1];      // int32 per harness contract
    const float* Wg = (const float*)d_in[2];
    const float* bg = (const float*)d_in[3];
    const float* Ws = (const float*)d_in[4];
    const float* bs = (const float*)d_in[5];
    const float* Wr = (const float*)d_in[6];
    const float* br = (const float*)d_in[7];
    float* out = (float*)d_out;

    const int N = in_sizes[0] / FD;       // 100000
    const int E = in_sizes[1] / 2;        // 600000

    // Workspace layout:
    //   Wf [512*128 bf16] | A [N*128 bf16] | BS [N*256 bf16] | deg/off [N int]
    //   | partial [264 int] | csr [E int]
    unsigned short* Wf  = (unsigned short*)d_ws;
    unsigned short* Abf = Wf + 512 * FD;
    unsigned short* BSb = Abf + (size_t)N * FD;
    int* deg     = (int*)(BSb + (size_t)N * 2 * FD);   // becomes off
    int* partial = deg + N;
    int* csr     = partial + 264;

    size_t need = (size_t)(512 * FD + 3ull * N * FD) * 2 + ((size_t)N + 264 + E) * 4;
    if (ws_size < need) return;   // diagnostic: absmax will equal memset-0 baseline

    const int nb = (N + 1023) / 1024;     // 98 scan chunks (<= 256 required)
    if (nb > 256) return;

    prep_kernel<<<256, 256, 0, stream>>>(Wg, Ws, Wr, Wf, deg, partial, N);
    dim3 ggrid(256, 6);   // y=0 hist (first), y=1..4 gemm, y=5 scan (last)
    gemm_kernel<<<ggrid, 256, 0, stream>>>(h, Wf, bg, bs, br,
                                           Abf, BSb, out, ei, deg, partial,
                                           N, E);
    scatter_kernel<<<(E + 255) / 256, 256, 0, stream>>>(ei, deg, csr, E);
    aggregate_kernel<<<(N + 3) / 4, 256, 0, stream>>>(deg, csr,
                                                      (const unsigned*)Abf,
                                                      (const unsigned*)BSb,
                                                      out, N);
}